// Round 9
// baseline (114.525 us; speedup 1.0000x reference)
//
#include <hip/hip_runtime.h>
#include <hip/hip_bf16.h>
#include <stdint.h>
#include <math.h>

// DynaLoRALinear bf16-MFMA. prep -> h-GEMM(+MFMA router partials) ->
// w-GEMM(+fused softmax) -> out-GEMM.  out = [x|w] @ [Wb^T;B2], K=1088.
// gemm8p: 8-phase, one-phase-ahead frag prefetch, launch_bounds(512,1)
// (LDS already limits to 1 block/CU; the old (512,2) only capped VGPR=128
// and forced the round-5 schedule to spill — FETCH +8MB signature).

#define M_TOK 16384

typedef unsigned short u16;
typedef short bf16x8 __attribute__((ext_vector_type(8)));
typedef float f32x4 __attribute__((ext_vector_type(4)));
typedef __attribute__((address_space(3))) uint32_t lds_u32_t;
typedef __attribute__((address_space(1))) const uint32_t glb_u32_t;

__device__ __forceinline__ u16 f2bf(float f) {
  uint32_t u = __builtin_bit_cast(uint32_t, f);
  return (u16)((u + 0x7fffu + ((u >> 16) & 1u)) >> 16);  // RNE
}
__device__ __forceinline__ float bf2f(u16 v) {
  return __builtin_bit_cast(float, (uint32_t)v << 16);
}

// ---------------- fused prep: all f32->bf16 conversions + gathers ----------------
__global__ __launch_bounds__(256) void prep_k(const float* __restrict__ x,
                                              const float* __restrict__ Wb,
                                              const float* __restrict__ rW1,
                                              const float* __restrict__ rW2,
                                              const float* __restrict__ loraA,
                                              const float* __restrict__ loraB,
                                              u16* __restrict__ xb,
                                              u16* __restrict__ Btb,
                                              u16* __restrict__ W1b,
                                              u16* __restrict__ W2b,
                                              u16* __restrict__ A2b) {
  const int g = blockIdx.x;
  const int tid = threadIdx.x;
  if (g < 16384) {
    int i = g * 256 + tid;
    float4 v = ((const float4*)x)[i];
    ushort4 o;
    o.x = f2bf(v.x); o.y = f2bf(v.y); o.z = f2bf(v.z); o.w = f2bf(v.w);
    ((ushort4*)xb)[i] = o;
  } else if (g < 17408) {
    int i = (g - 16384) * 256 + tid;
    int idx = i * 4;
    int row = idx >> 10, col = idx & 1023;
    float4 v = ((const float4*)Wb)[i];
    ushort4 o;
    o.x = f2bf(v.x); o.y = f2bf(v.y); o.z = f2bf(v.z); o.w = f2bf(v.w);
    *(ushort4*)(Btb + (size_t)row * 1088 + col) = o;
  } else if (g < 17920) {
    int i = (g - 17408) * 256 + tid;
    float4 v = ((const float4*)rW1)[i];
    ushort4 o;
    o.x = f2bf(v.x); o.y = f2bf(v.y); o.z = f2bf(v.z); o.w = f2bf(v.w);
    ((ushort4*)W1b)[i] = o;
  } else if (g < 18176) {
    int idx = (g - 17920) * 256 + tid;
    int n = idx >> 6, q = idx & 63;
    int e = q >> 3, r = q & 7;
    Btb[(size_t)n * 1088 + 1024 + q] = f2bf(loraB[((size_t)(e * 1024 + n)) * 8 + r]);
  } else if (g < 18240) {
    int i = (g - 18176) * 256 + tid;
    float4 v = ((const float4*)loraA)[i];
    ushort4 o;
    o.x = f2bf(v.x); o.y = f2bf(v.y); o.z = f2bf(v.z); o.w = f2bf(v.w);
    ((ushort4*)A2b)[i] = o;
  } else {
    // W2b [16][512] bf16, rows 8..15 zero (MFMA B-operand pad)
    int i = (g - 18240) * 256 + tid;  // 2048 ushort4 slots
    int idx = i * 4;
    int row = idx >> 9, col = idx & 511;
    ushort4 o = {0, 0, 0, 0};
    if (row < 8) {
      float4 v = *(const float4*)(rW2 + (size_t)row * 512 + col);
      o.x = f2bf(v.x); o.y = f2bf(v.y); o.z = f2bf(v.z); o.w = f2bf(v.w);
    }
    ((ushort4*)W2b)[i] = o;
  }
}

// ---------------- w-GEMM with fused gate softmax ----------------
// w = (x @ A^T) * gate, 64x64 tile, 4 waves (2x2), m97-style K-loop.
// Prologue: gates for the block's 64 tokens from 4 partial-logit slices.
__global__ __launch_bounds__(256) void gemm_w(const u16* __restrict__ A,
                                              const u16* __restrict__ Bt,
                                              const float* __restrict__ part,
                                              const float* __restrict__ b2,
                                              const float* __restrict__ temp,
                                              u16* __restrict__ Cv) {
  constexpr int BM = 64, BN = 64, FM = 2, FN = 2, AI = 2, BI = 2;
  __shared__ u16 lds[(BM + BN) * 64];
  __shared__ float g_lds[64][8];
  u16* As = lds;
  u16* Bs = lds + BM * 64;

  const int tid = threadIdx.x;
  const int w = tid >> 6, lane = tid & 63;
  const int wr = w >> 1, wc = w & 1;
  const int m0 = blockIdx.y * BM;

  // ---- softmax prologue: 64 threads, one token each ----
  if (tid < 64) {
    const int m = m0 + tid;
    float lg[8] = {};
#pragma unroll
    for (int q = 0; q < 4; ++q) {
      const float4* pp = (const float4*)(part + ((size_t)q * M_TOK + m) * 8);
      float4 a = pp[0], b = pp[1];
      lg[0] += a.x; lg[1] += a.y; lg[2] += a.z; lg[3] += a.w;
      lg[4] += b.x; lg[5] += b.y; lg[6] += b.z; lg[7] += b.w;
    }
    float t = temp[0], mx = -1e30f;
#pragma unroll
    for (int e = 0; e < 8; ++e) { lg[e] = (lg[e] + b2[e]) / t; mx = fmaxf(mx, lg[e]); }
    float s = 0.f;
#pragma unroll
    for (int e = 0; e < 8; ++e) { lg[e] = expf(lg[e] - mx); s += lg[e]; }
    float inv = 1.f / s;
#pragma unroll
    for (int e = 0; e < 8; ++e) g_lds[tid][e] = lg[e] * inv;
  }

  const uint8_t* Ab = (const uint8_t*)A;
  const uint8_t* Bb = (const uint8_t*)Bt;
  f32x4 acc[FM][FN] = {};

  for (int kt = 0; kt < 16; ++kt) {
#pragma unroll
    for (int i = 0; i < AI; ++i) {
      const int lbase = (w * AI + i) * 1024;
      const int o = lbase + lane * 16;
      const int r = o >> 7, cb = o & 127;
      const uint8_t* g = Ab + (size_t)(m0 + r) * 2048 + (size_t)kt * 128 + cb;
      __builtin_amdgcn_global_load_lds((glb_u32_t*)g,
                                       (lds_u32_t*)((uint8_t*)As + lbase), 16, 0, 0);
    }
#pragma unroll
    for (int i = 0; i < BI; ++i) {
      const int lbase = (w * BI + i) * 1024;
      const int o = lbase + lane * 16;
      const int r = o >> 7, cb = o & 127;
      const uint8_t* g = Bb + (size_t)r * 2048 + (size_t)kt * 128 + cb;
      __builtin_amdgcn_global_load_lds((glb_u32_t*)g,
                                       (lds_u32_t*)((uint8_t*)Bs + lbase), 16, 0, 0);
    }
    __syncthreads();

    bf16x8 af[2][FM], bfv[2][FN];
#pragma unroll
    for (int ks = 0; ks < 2; ++ks) {
      const int col = ks * 32 + ((lane >> 4) << 3);
#pragma unroll
      for (int im = 0; im < FM; ++im) {
        const int row = wr * 32 + im * 16 + (lane & 15);
        af[ks][im] = *(const bf16x8*)(As + row * 64 + col);
      }
#pragma unroll
      for (int in_ = 0; in_ < FN; ++in_) {
        const int row = wc * 32 + in_ * 16 + (lane & 15);
        bfv[ks][in_] = *(const bf16x8*)(Bs + row * 64 + col);
      }
    }
#pragma unroll
    for (int ks = 0; ks < 2; ++ks)
#pragma unroll
      for (int im = 0; im < FM; ++im)
#pragma unroll
        for (int in_ = 0; in_ < FN; ++in_)
          acc[im][in_] = __builtin_amdgcn_mfma_f32_16x16x32_bf16(
              af[ks][im], bfv[ks][in_], acc[im][in_], 0, 0, 0);
    __syncthreads();
  }

#pragma unroll
  for (int im = 0; im < FM; ++im)
#pragma unroll
    for (int in_ = 0; in_ < FN; ++in_) {
      const int col = wc * 32 + in_ * 16 + (lane & 15);
#pragma unroll
      for (int j = 0; j < 4; ++j) {
        const int lrow = wr * 32 + im * 16 + ((lane >> 4) << 2) + j;
        float v = acc[im][in_][j] * g_lds[lrow][col >> 3];
        Cv[(size_t)(m0 + lrow) * 64 + col] = f2bf(v);
      }
    }
}

// ============ 8-phase GEMM, one-phase-ahead frag prefetch, counted vmcnt ============
// Phase p: [stage future half-tile][VMCNT @P4/P8][BAR][ds_reads for phase p+1]
//          [SP1; MFMA consuming frags read at p-1; SP0][BAR]
// MODE 3: h-GEMM — epilogue spills relu(h) to LDS, MFMA router partials (no hb).
// MODE 2: out-GEMM — last K-tile's A from A2 (128B rows), plain f32 store.
#define MFMA_Q2(mh, nh, AF, BF)                                                \
  _Pragma("unroll") for (int im2 = 0; im2 < FMH; ++im2)                        \
  _Pragma("unroll") for (int in2 = 0; in2 < FNH; ++in2)                        \
  _Pragma("unroll") for (int ks = 0; ks < 2; ++ks)                             \
      acc[(mh) * FMH + im2][(nh) * FNH + in2] =                                \
          __builtin_amdgcn_mfma_f32_16x16x32_bf16(                             \
              AF[im2][ks], BF[in2][ks],                                        \
              acc[(mh) * FMH + im2][(nh) * FNH + in2], 0, 0, 0);

#define VMCNT(n) asm volatile("s_waitcnt vmcnt(%0)" ::"i"(n) : "memory")
#define BAR asm volatile("s_barrier" ::: "memory")
#define SP(x) __builtin_amdgcn_s_setprio(x)

template <int BM, int BN, int MODE>
__global__ __launch_bounds__(512, 1) void gemm8p(const u16* __restrict__ A,
                                                 const u16* __restrict__ Bt,
                                                 const u16* __restrict__ A2,
                                                 void* __restrict__ Cv,
                                                 const float* __restrict__ aux,
                                                 const int N, const int K,
                                                 const int lda, const int ldb) {
  constexpr int FM = BM / 32;
  constexpr int FNW = BN / 64;
  constexpr int FMH = FM / 2;
  constexpr int FNH = (FNW >= 2) ? FNW / 2 : 1;
  constexpr int NBH = BN / 128;
  constexpr int VMC = 2 * NBH;
  constexpr int BUFB = (BM + BN) * 128;

  __shared__ __align__(16) uint8_t lds[2 * BUFB];

  const int tid = threadIdx.x;
  const int lane = tid & 63, w = tid >> 6;
  const int wr = w >> 2, wcn = w & 3;
  const int l15 = lane & 15, lhi = lane >> 4;
  const int xorv = (lane & 7) << 4;
  const int c0 = (lhi * 16) ^ xorv;
  const int c1 = (64 + lhi * 16) ^ xorv;

  // T1: bijective XCD swizzle (grid = 256 = 32/XCD).
  const int f = blockIdx.x;
  const int idx = (f & 7) * 32 + (f >> 3);
  const int gx = N / BN;
  const int m0 = (idx / gx) * BM;
  const int n0 = (idx % gx) * BN;

  const size_t lda_b = (size_t)lda * 2, ldb_b = (size_t)ldb * 2;
  const int nk = K >> 6;

  const int arow0 = (wr * (BM / 2) + l15) * 128;
  const int brow0 = (wcn * (BN / 4) + l15) * 128;

  f32x4 acc[FM][FNW] = {};
  bf16x8 A0f[FMH][2], A1f[FMH][2];
  bf16x8 B0a[FNH][2], B0b[FNH][2], B1f[FNH][2];

  auto stageA = [&](int h, int kt, int b) {
    const int ktc = kt < nk ? kt : nk - 1;
    const bool last = (MODE == 2) && (ktc == nk - 1);
    uint8_t* dst = lds + b * BUFB + h * (BM * 64) + w * 1024;
#pragma unroll
    for (int i = 0; i < 2; ++i) {
      const int off = i * 8192 + tid * 16;
      const int row = h * (BM / 2) + (off >> 7);
      const int ss = ((off >> 4) & 7) ^ (row & 7);
      const uint8_t* g =
          last ? (const uint8_t*)A2 + (size_t)(m0 + row) * 128 + ss * 16
               : (const uint8_t*)A + (size_t)(m0 + row) * lda_b + ktc * 128 + ss * 16;
      __builtin_amdgcn_global_load_lds((glb_u32_t*)g, (lds_u32_t*)(dst + i * 8192),
                                       16, 0, 0);
    }
  };
  auto stageB = [&](int h, int kt, int b) {
    const int ktc = kt < nk ? kt : nk - 1;
    uint8_t* dst = lds + b * BUFB + BM * 128 + h * (BN * 64) + w * 1024;
#pragma unroll
    for (int i = 0; i < 2; ++i) {
      const int off = i * 8192 + tid * 16;
      const int row = h * (BN / 2) + (off >> 7);
      const int ss = ((off >> 4) & 7) ^ (row & 7);
      const uint8_t* g =
          (const uint8_t*)Bt + (size_t)(n0 + row) * ldb_b + ktc * 128 + ss * 16;
      __builtin_amdgcn_global_load_lds((glb_u32_t*)g, (lds_u32_t*)(dst + i * 8192),
                                       16, 0, 0);
    }
  };

  auto loadA = [&](int mh, const uint8_t* buf, bf16x8 (&dst)[FMH][2]) {
#pragma unroll
    for (int im2 = 0; im2 < FMH; ++im2) {
      const uint8_t* p = buf + arow0 + mh * (FMH * 2048) + im2 * 2048;
      dst[im2][0] = *(const bf16x8*)(p + c0);
      dst[im2][1] = *(const bf16x8*)(p + c1);
    }
  };
  auto loadB = [&](int nh, const uint8_t* buf, bf16x8 (&dst)[FNH][2]) {
#pragma unroll
    for (int in2 = 0; in2 < FNH; ++in2) {
      const uint8_t* p = buf + BM * 128 + brow0 + nh * (FNH * 2048) + in2 * 2048;
      dst[in2][0] = *(const bf16x8*)(p + c0);
      dst[in2][1] = *(const bf16x8*)(p + c1);
    }
  };

  const uint8_t* b0 = lds;
  const uint8_t* b1 = lds + BUFB;

  // ---- prologue: tile0 (A+B) -> buf0, tile1 B -> buf1; pre-read A0,B0(0) ----
  stageA(0, 0, 0); stageA(1, 0, 0);
  stageB(0, 0, 0); if constexpr (NBH == 2) stageB(1, 0, 0);
  stageB(0, 1, 1); if constexpr (NBH == 2) stageB(1, 1, 1);
  VMCNT(VMC); BAR;
  loadA(0, b0, A0f); loadB(0, b0, B0a);

  const int NIT = nk >> 1;
  for (int it = 0; it < NIT; ++it) {
    const int t = it * 2;
    // P1: MFMA Q(0,0|t); read B1(t)
    stageA(0, t + 1, 1);
    BAR;
    loadB(1, b0, B1f);
    SP(1); MFMA_Q2(0, 0, A0f, B0a); SP(0); BAR;
    // P2: Q(0,1|t); read A1(t)
    stageA(1, t + 1, 1);
    BAR;
    loadA(1, b0, A1f);
    SP(1); MFMA_Q2(0, 1, A0f, B1f); SP(0); BAR;
    // P3: Q(1,1|t); no reads
    stageB(0, t + 2, 0);
    BAR;
    SP(1); MFMA_Q2(1, 1, A1f, B1f); SP(0); BAR;
    // P4: Q(1,0|t); vmcnt completes tile t+1 -> read A0,B0(t+1)
    if constexpr (NBH == 2) stageB(1, t + 2, 0);
    VMCNT(VMC);
    BAR;
    loadA(0, b1, A0f); loadB(0, b1, B0b);
    SP(1); MFMA_Q2(1, 0, A1f, B0a); SP(0); BAR;
    // P5: Q(0,0|t+1); read B1(t+1)
    stageA(0, t + 2, 0);
    BAR;
    loadB(1, b1, B1f);
    SP(1); MFMA_Q2(0, 0, A0f, B0b); SP(0); BAR;
    // P6: Q(0,1|t+1); read A1(t+1)
    stageA(1, t + 2, 0);
    BAR;
    loadA(1, b1, A1f);
    SP(1); MFMA_Q2(0, 1, A0f, B1f); SP(0); BAR;
    // P7: Q(1,1|t+1); no reads
    stageB(0, t + 3, 1);
    BAR;
    SP(1); MFMA_Q2(1, 1, A1f, B1f); SP(0); BAR;
    // P8: Q(1,0|t+1); vmcnt completes tile t+2 -> read A0,B0(t+2)
    if constexpr (NBH == 2) stageB(1, t + 3, 1);
    VMCNT(VMC);
    BAR;
    loadA(0, b0, A0f); loadB(0, b0, B0a);
    SP(1); MFMA_Q2(1, 0, A1f, B0b); SP(0); BAR;
  }

  // ---- tail K-tile (odd nk): buf0 holds tile nk-1; A0f/B0a pre-read at last P8 ----
  if (nk & 1) {
    loadB(1, b0, B1f);
    SP(1); MFMA_Q2(0, 0, A0f, B0a); SP(0);
    loadA(1, b0, A1f);
    SP(1); MFMA_Q2(0, 1, A0f, B1f); SP(0);
    SP(1); MFMA_Q2(1, 1, A1f, B1f); MFMA_Q2(1, 0, A1f, B0a); SP(0);
  }

  // ---- epilogue ----
  if constexpr (MODE == 2) {
    // out: plain f32 stores. C/D map col=lane&15, row=(lane>>4)*4+j.
    float* C = (float*)Cv;
#pragma unroll
    for (int im = 0; im < FM; ++im) {
#pragma unroll
      for (int in_ = 0; in_ < FNW; ++in_) {
        const int col = n0 + wcn * (BN / 4) + in_ * 16 + l15;
#pragma unroll
        for (int j = 0; j < 4; ++j) {
          const int row = m0 + wr * (BM / 2) + im * 16 + lhi * 4 + j;
          C[(size_t)row * N + col] = acc[im][in_][j];
        }
      }
    }
  } else {
    // MODE 3 (h, BM=256/BN=128): spill relu(h+b1) -> LDS hs[256][132] bf16,
    // then logits-GEMM vs W2b (bf16 [16][512], rows 8..15 zero) via MFMA.
    u16* hs = (u16*)lds;
    __syncthreads();  // drains vmcnt/lgkm (in-flight clamped prefetches) + barrier
#pragma unroll
    for (int im = 0; im < FM; ++im) {
#pragma unroll
      for (int in_ = 0; in_ < FNW; ++in_) {
        const int col = wcn * (BN / 4) + in_ * 16 + l15;  // block-local col
#pragma unroll
        for (int j = 0; j < 4; ++j) {
          const int row = wr * (BM / 2) + im * 16 + lhi * 4 + j;
          float v = fmaxf(acc[im][in_][j] + aux[n0 + col], 0.f);
          hs[row * 132 + col] = f2bf(v);
        }
      }
    }
    __syncthreads();
    // logits[256 x 8] = hs[256 x 128] @ W2b[.., n0..n0+127]^T. Wave w: rows w*32..+32.
    const u16* w2b = (const u16*)A2;
    f32x4 acc2[2] = {};
#pragma unroll
    for (int ks = 0; ks < 4; ++ks) {
      bf16x8 bfrag = *(const bf16x8*)(w2b + (size_t)l15 * 512 + n0 + ks * 32 + lhi * 8);
#pragma unroll
      for (int im2 = 0; im2 < 2; ++im2) {
        const int mrow = w * 32 + im2 * 16 + l15;
        bf16x8 afrag = *(const bf16x8*)(hs + mrow * 132 + ks * 32 + lhi * 8);
        acc2[im2] = __builtin_amdgcn_mfma_f32_16x16x32_bf16(afrag, bfrag, acc2[im2],
                                                            0, 0, 0);
      }
    }
    if (l15 < 8) {
      float* part = (float*)Cv;
      const size_t base = (size_t)(n0 >> 7) * M_TOK;
#pragma unroll
      for (int im2 = 0; im2 < 2; ++im2)
#pragma unroll
        for (int j = 0; j < 4; ++j) {
          const int row = m0 + w * 32 + im2 * 16 + lhi * 4 + j;
          part[(base + row) * 8 + l15] = acc2[im2][j];
        }
    }
  }
}

extern "C" void kernel_launch(void* const* d_in, const int* in_sizes, int n_in,
                              void* d_out, int out_size, void* d_ws, size_t ws_size,
                              hipStream_t stream) {
  const float* x     = (const float*)d_in[0];  // [16384][1024]
  const float* Wb    = (const float*)d_in[1];  // [1024][1024]
  const float* rW1   = (const float*)d_in[2];  // [512][1024]
  const float* rb1   = (const float*)d_in[3];  // [512]
  const float* rW2   = (const float*)d_in[4];  // [8][512]
  const float* rb2   = (const float*)d_in[5];  // [8]
  const float* temp  = (const float*)d_in[6];  // [1]
  const float* loraA = (const float*)d_in[7];  // [64][1024]
  const float* loraB = (const float*)d_in[8];  // [8][1024][8]
  float* out = (float*)d_out;

  uint8_t* p = (uint8_t*)d_ws;
  u16* xb    = (u16*)p;   p += (size_t)M_TOK * 1024 * 2;
  u16* wb    = (u16*)p;   p += (size_t)M_TOK * 64 * 2;
  u16* Btb   = (u16*)p;   p += (size_t)1024 * 1088 * 2;
  u16* W1b   = (u16*)p;   p += (size_t)512 * 1024 * 2;
  u16* W2b   = (u16*)p;   p += (size_t)16 * 512 * 2;
  u16* A2b   = (u16*)p;   p += (size_t)64 * 1024 * 2;
  float* part = (float*)p;  // [4][16384][8] f32 = 2 MB

  // ---- fused prep (incl. W2 -> bf16 padded [16][512]) ----
  prep_k<<<18248, 256, 0, stream>>>(x, Wb, rW1, rW2, loraA, loraB,
                                    xb, Btb, W1b, W2b, A2b);

  // ---- h-GEMM: MFMA router partials, no h materialization ----
  gemm8p<256, 128, 3><<<256, 512, 0, stream>>>(xb, W1b, (const u16*)W2b, part,
                                               rb1, 512, 1024, 1024, 1024);

  // ---- w = (x @ A^T) * softmax-gates (fused) -> bf16 [16384][64] ----
  gemm_w<<<dim3(1, M_TOK / 64), 256, 0, stream>>>(xb, A2b, part, rb2, temp, wb);

  // ---- out = [x | w] @ [Wb^T ; B2] -> f32, K=1088 ----
  gemm8p<256, 256, 2><<<256, 512, 0, stream>>>(xb, Btb, wb, out, nullptr,
                                               1024, 1088, 1024, 1088);
}

// Round 10
// 93.836 us; speedup vs baseline: 1.2205x; 1.2205x over previous
//
#include <hip/hip_runtime.h>
#include <hip/hip_bf16.h>
#include <stdint.h>
#include <math.h>

// DynaLoRALinear bf16-MFMA. prep -> h-GEMM(+MFMA router partials) ->
// w-GEMM(+fused softmax) -> out-GEMM.  out = [x|w] @ [Wb^T;B2], K=1088.
// gemm8p: 8-phase, POST-MFMA frag reads (consumed next phase, single reg sets).

#define M_TOK 16384

typedef unsigned short u16;
typedef short bf16x8 __attribute__((ext_vector_type(8)));
typedef float f32x4 __attribute__((ext_vector_type(4)));
typedef __attribute__((address_space(3))) uint32_t lds_u32_t;
typedef __attribute__((address_space(1))) const uint32_t glb_u32_t;

__device__ __forceinline__ u16 f2bf(float f) {
  uint32_t u = __builtin_bit_cast(uint32_t, f);
  return (u16)((u + 0x7fffu + ((u >> 16) & 1u)) >> 16);  // RNE
}
__device__ __forceinline__ float bf2f(u16 v) {
  return __builtin_bit_cast(float, (uint32_t)v << 16);
}

// ---------------- fused prep: all f32->bf16 conversions + gathers ----------------
__global__ __launch_bounds__(256) void prep_k(const float* __restrict__ x,
                                              const float* __restrict__ Wb,
                                              const float* __restrict__ rW1,
                                              const float* __restrict__ rW2,
                                              const float* __restrict__ loraA,
                                              const float* __restrict__ loraB,
                                              u16* __restrict__ xb,
                                              u16* __restrict__ Btb,
                                              u16* __restrict__ W1b,
                                              u16* __restrict__ W2b,
                                              u16* __restrict__ A2b) {
  const int g = blockIdx.x;
  const int tid = threadIdx.x;
  if (g < 16384) {
    int i = g * 256 + tid;
    float4 v = ((const float4*)x)[i];
    ushort4 o;
    o.x = f2bf(v.x); o.y = f2bf(v.y); o.z = f2bf(v.z); o.w = f2bf(v.w);
    ((ushort4*)xb)[i] = o;
  } else if (g < 17408) {
    int i = (g - 16384) * 256 + tid;
    int idx = i * 4;
    int row = idx >> 10, col = idx & 1023;
    float4 v = ((const float4*)Wb)[i];
    ushort4 o;
    o.x = f2bf(v.x); o.y = f2bf(v.y); o.z = f2bf(v.z); o.w = f2bf(v.w);
    *(ushort4*)(Btb + (size_t)row * 1088 + col) = o;
  } else if (g < 17920) {
    int i = (g - 17408) * 256 + tid;
    float4 v = ((const float4*)rW1)[i];
    ushort4 o;
    o.x = f2bf(v.x); o.y = f2bf(v.y); o.z = f2bf(v.z); o.w = f2bf(v.w);
    ((ushort4*)W1b)[i] = o;
  } else if (g < 18176) {
    int idx = (g - 17920) * 256 + tid;
    int n = idx >> 6, q = idx & 63;
    int e = q >> 3, r = q & 7;
    Btb[(size_t)n * 1088 + 1024 + q] = f2bf(loraB[((size_t)(e * 1024 + n)) * 8 + r]);
  } else if (g < 18240) {
    int i = (g - 18176) * 256 + tid;
    float4 v = ((const float4*)loraA)[i];
    ushort4 o;
    o.x = f2bf(v.x); o.y = f2bf(v.y); o.z = f2bf(v.z); o.w = f2bf(v.w);
    ((ushort4*)A2b)[i] = o;
  } else {
    // W2b [16][512] bf16, rows 8..15 zero (MFMA B-operand pad)
    int i = (g - 18240) * 256 + tid;  // 2048 ushort4 slots
    int idx = i * 4;
    int row = idx >> 9, col = idx & 511;
    ushort4 o = {0, 0, 0, 0};
    if (row < 8) {
      float4 v = *(const float4*)(rW2 + (size_t)row * 512 + col);
      o.x = f2bf(v.x); o.y = f2bf(v.y); o.z = f2bf(v.z); o.w = f2bf(v.w);
    }
    ((ushort4*)W2b)[i] = o;
  }
}

// ---------------- w-GEMM with fused gate softmax ----------------
// w = (x @ A^T) * gate, 64x64 tile, 4 waves (2x2), m97-style K-loop.
// Prologue: gates for the block's 64 tokens from 4 partial-logit slices.
__global__ __launch_bounds__(256) void gemm_w(const u16* __restrict__ A,
                                              const u16* __restrict__ Bt,
                                              const float* __restrict__ part,
                                              const float* __restrict__ b2,
                                              const float* __restrict__ temp,
                                              u16* __restrict__ Cv) {
  constexpr int BM = 64, BN = 64, FM = 2, FN = 2, AI = 2, BI = 2;
  __shared__ u16 lds[(BM + BN) * 64];
  __shared__ float g_lds[64][8];
  u16* As = lds;
  u16* Bs = lds + BM * 64;

  const int tid = threadIdx.x;
  const int w = tid >> 6, lane = tid & 63;
  const int wr = w >> 1, wc = w & 1;
  const int m0 = blockIdx.y * BM;

  // ---- softmax prologue: 64 threads, one token each ----
  if (tid < 64) {
    const int m = m0 + tid;
    float lg[8] = {};
#pragma unroll
    for (int q = 0; q < 4; ++q) {
      const float4* pp = (const float4*)(part + ((size_t)q * M_TOK + m) * 8);
      float4 a = pp[0], b = pp[1];
      lg[0] += a.x; lg[1] += a.y; lg[2] += a.z; lg[3] += a.w;
      lg[4] += b.x; lg[5] += b.y; lg[6] += b.z; lg[7] += b.w;
    }
    float t = temp[0], mx = -1e30f;
#pragma unroll
    for (int e = 0; e < 8; ++e) { lg[e] = (lg[e] + b2[e]) / t; mx = fmaxf(mx, lg[e]); }
    float s = 0.f;
#pragma unroll
    for (int e = 0; e < 8; ++e) { lg[e] = expf(lg[e] - mx); s += lg[e]; }
    float inv = 1.f / s;
#pragma unroll
    for (int e = 0; e < 8; ++e) g_lds[tid][e] = lg[e] * inv;
  }

  const uint8_t* Ab = (const uint8_t*)A;
  const uint8_t* Bb = (const uint8_t*)Bt;
  f32x4 acc[FM][FN] = {};

  for (int kt = 0; kt < 16; ++kt) {
#pragma unroll
    for (int i = 0; i < AI; ++i) {
      const int lbase = (w * AI + i) * 1024;
      const int o = lbase + lane * 16;
      const int r = o >> 7, cb = o & 127;
      const uint8_t* g = Ab + (size_t)(m0 + r) * 2048 + (size_t)kt * 128 + cb;
      __builtin_amdgcn_global_load_lds((glb_u32_t*)g,
                                       (lds_u32_t*)((uint8_t*)As + lbase), 16, 0, 0);
    }
#pragma unroll
    for (int i = 0; i < BI; ++i) {
      const int lbase = (w * BI + i) * 1024;
      const int o = lbase + lane * 16;
      const int r = o >> 7, cb = o & 127;
      const uint8_t* g = Bb + (size_t)r * 2048 + (size_t)kt * 128 + cb;
      __builtin_amdgcn_global_load_lds((glb_u32_t*)g,
                                       (lds_u32_t*)((uint8_t*)Bs + lbase), 16, 0, 0);
    }
    __syncthreads();

    bf16x8 af[2][FM], bfv[2][FN];
#pragma unroll
    for (int ks = 0; ks < 2; ++ks) {
      const int col = ks * 32 + ((lane >> 4) << 3);
#pragma unroll
      for (int im = 0; im < FM; ++im) {
        const int row = wr * 32 + im * 16 + (lane & 15);
        af[ks][im] = *(const bf16x8*)(As + row * 64 + col);
      }
#pragma unroll
      for (int in_ = 0; in_ < FN; ++in_) {
        const int row = wc * 32 + in_ * 16 + (lane & 15);
        bfv[ks][in_] = *(const bf16x8*)(Bs + row * 64 + col);
      }
    }
#pragma unroll
    for (int ks = 0; ks < 2; ++ks)
#pragma unroll
      for (int im = 0; im < FM; ++im)
#pragma unroll
        for (int in_ = 0; in_ < FN; ++in_)
          acc[im][in_] = __builtin_amdgcn_mfma_f32_16x16x32_bf16(
              af[ks][im], bfv[ks][in_], acc[im][in_], 0, 0, 0);
    __syncthreads();
  }

#pragma unroll
  for (int im = 0; im < FM; ++im)
#pragma unroll
    for (int in_ = 0; in_ < FN; ++in_) {
      const int col = wc * 32 + in_ * 16 + (lane & 15);
#pragma unroll
      for (int j = 0; j < 4; ++j) {
        const int lrow = wr * 32 + im * 16 + ((lane >> 4) << 2) + j;
        float v = acc[im][in_][j] * g_lds[lrow][col >> 3];
        Cv[(size_t)(m0 + lrow) * 64 + col] = f2bf(v);
      }
    }
}

// ============ 8-phase GEMM, POST-MFMA frag reads, counted vmcnt ============
// Phase p: [stage 1 half-tile][VMCNT @P4/P8][BAR][SP1; MFMA (frags read at p-1);
//          SP0][ds_reads for phase p+1][BAR]
// Even read distribution; MFMA never drains same-phase reads. Single reg sets
// (WAR resolved by program order). Stage-overwrite vs last-read: >=2 barriers.
// MODE 3: h-GEMM — epilogue spills relu(h) to LDS, MFMA router partials.
// MODE 2: out-GEMM — last K-tile's A from A2 (128B rows), f32 store.
#define MFMA_Q2(mh, nh, AF, BF)                                                \
  _Pragma("unroll") for (int im2 = 0; im2 < FMH; ++im2)                        \
  _Pragma("unroll") for (int in2 = 0; in2 < FNH; ++in2)                        \
  _Pragma("unroll") for (int ks = 0; ks < 2; ++ks)                             \
      acc[(mh) * FMH + im2][(nh) * FNH + in2] =                                \
          __builtin_amdgcn_mfma_f32_16x16x32_bf16(                             \
              AF[im2][ks], BF[in2][ks],                                        \
              acc[(mh) * FMH + im2][(nh) * FNH + in2], 0, 0, 0);

#define VMCNT(n) asm volatile("s_waitcnt vmcnt(%0)" ::"i"(n) : "memory")
#define BAR asm volatile("s_barrier" ::: "memory")
#define SP(x) __builtin_amdgcn_s_setprio(x)

template <int BM, int BN, int MODE>
__global__ __launch_bounds__(512, 2) void gemm8p(const u16* __restrict__ A,
                                                 const u16* __restrict__ Bt,
                                                 const u16* __restrict__ A2,
                                                 void* __restrict__ Cv,
                                                 const float* __restrict__ aux,
                                                 const int N, const int K,
                                                 const int lda, const int ldb) {
  constexpr int FM = BM / 32;
  constexpr int FNW = BN / 64;
  constexpr int FMH = FM / 2;
  constexpr int FNH = (FNW >= 2) ? FNW / 2 : 1;
  constexpr int NBH = BN / 128;
  constexpr int VMC = 2 * NBH;
  constexpr int BUFB = (BM + BN) * 128;

  __shared__ __align__(16) uint8_t lds[2 * BUFB];

  const int tid = threadIdx.x;
  const int lane = tid & 63, w = tid >> 6;
  const int wr = w >> 2, wcn = w & 3;
  const int l15 = lane & 15, lhi = lane >> 4;
  const int xorv = (lane & 7) << 4;
  const int c0 = (lhi * 16) ^ xorv;
  const int c1 = (64 + lhi * 16) ^ xorv;

  // T1: bijective XCD swizzle (grid = 256 = 32/XCD).
  const int f = blockIdx.x;
  const int idx = (f & 7) * 32 + (f >> 3);
  const int gx = N / BN;
  const int m0 = (idx / gx) * BM;
  const int n0 = (idx % gx) * BN;

  const size_t lda_b = (size_t)lda * 2, ldb_b = (size_t)ldb * 2;
  const int nk = K >> 6;

  const int arow0 = (wr * (BM / 2) + l15) * 128;
  const int brow0 = (wcn * (BN / 4) + l15) * 128;

  f32x4 acc[FM][FNW] = {};
  bf16x8 A0f[FMH][2], A1f[FMH][2];
  bf16x8 B0f[FNH][2], B1f[FNH][2];

  auto stageA = [&](int h, int kt, int b) {
    const int ktc = kt < nk ? kt : nk - 1;
    const bool last = (MODE == 2) && (ktc == nk - 1);
    uint8_t* dst = lds + b * BUFB + h * (BM * 64) + w * 1024;
#pragma unroll
    for (int i = 0; i < 2; ++i) {
      const int off = i * 8192 + tid * 16;
      const int row = h * (BM / 2) + (off >> 7);
      const int ss = ((off >> 4) & 7) ^ (row & 7);
      const uint8_t* g =
          last ? (const uint8_t*)A2 + (size_t)(m0 + row) * 128 + ss * 16
               : (const uint8_t*)A + (size_t)(m0 + row) * lda_b + ktc * 128 + ss * 16;
      __builtin_amdgcn_global_load_lds((glb_u32_t*)g, (lds_u32_t*)(dst + i * 8192),
                                       16, 0, 0);
    }
  };
  auto stageB = [&](int h, int kt, int b) {
    const int ktc = kt < nk ? kt : nk - 1;
    uint8_t* dst = lds + b * BUFB + BM * 128 + h * (BN * 64) + w * 1024;
#pragma unroll
    for (int i = 0; i < 2; ++i) {
      const int off = i * 8192 + tid * 16;
      const int row = h * (BN / 2) + (off >> 7);
      const int ss = ((off >> 4) & 7) ^ (row & 7);
      const uint8_t* g =
          (const uint8_t*)Bt + (size_t)(n0 + row) * ldb_b + ktc * 128 + ss * 16;
      __builtin_amdgcn_global_load_lds((glb_u32_t*)g, (lds_u32_t*)(dst + i * 8192),
                                       16, 0, 0);
    }
  };

  auto loadA = [&](int mh, const uint8_t* buf, bf16x8 (&dst)[FMH][2]) {
#pragma unroll
    for (int im2 = 0; im2 < FMH; ++im2) {
      const uint8_t* p = buf + arow0 + mh * (FMH * 2048) + im2 * 2048;
      dst[im2][0] = *(const bf16x8*)(p + c0);
      dst[im2][1] = *(const bf16x8*)(p + c1);
    }
  };
  auto loadB = [&](int nh, const uint8_t* buf, bf16x8 (&dst)[FNH][2]) {
#pragma unroll
    for (int in2 = 0; in2 < FNH; ++in2) {
      const uint8_t* p = buf + BM * 128 + brow0 + nh * (FNH * 2048) + in2 * 2048;
      dst[in2][0] = *(const bf16x8*)(p + c0);
      dst[in2][1] = *(const bf16x8*)(p + c1);
    }
  };

  const uint8_t* b0 = lds;
  const uint8_t* b1 = lds + BUFB;

  // ---- prologue: tile0 (A+B) -> buf0, tile1 B -> buf1; pre-read A0,B0(0) ----
  stageA(0, 0, 0); stageA(1, 0, 0);
  stageB(0, 0, 0); if constexpr (NBH == 2) stageB(1, 0, 0);
  stageB(0, 1, 1); if constexpr (NBH == 2) stageB(1, 1, 1);
  VMCNT(VMC); BAR;
  loadA(0, b0, A0f); loadB(0, b0, B0f);

  const int NIT = nk >> 1;
  for (int it = 0; it < NIT; ++it) {
    const int t = it * 2;
    // P1: Q(0,0|t); post-read B1(t)
    stageA(0, t + 1, 1);
    BAR;
    SP(1); MFMA_Q2(0, 0, A0f, B0f); SP(0);
    loadB(1, b0, B1f);
    BAR;
    // P2: Q(0,1|t); post-read A1(t)
    stageA(1, t + 1, 1);
    BAR;
    SP(1); MFMA_Q2(0, 1, A0f, B1f); SP(0);
    loadA(1, b0, A1f);
    BAR;
    // P3: Q(1,1|t); no reads
    stageB(0, t + 2, 0);
    BAR;
    SP(1); MFMA_Q2(1, 1, A1f, B1f); SP(0);
    BAR;
    // P4: Q(1,0|t); VMCNT completes tile t+1 -> post-read A0,B0(t+1)
    if constexpr (NBH == 2) stageB(1, t + 2, 0);
    VMCNT(VMC);
    BAR;
    SP(1); MFMA_Q2(1, 0, A1f, B0f); SP(0);
    loadA(0, b1, A0f); loadB(0, b1, B0f);
    BAR;
    // P5: Q(0,0|t+1); post-read B1(t+1)
    stageA(0, t + 2, 0);
    BAR;
    SP(1); MFMA_Q2(0, 0, A0f, B0f); SP(0);
    loadB(1, b1, B1f);
    BAR;
    // P6: Q(0,1|t+1); post-read A1(t+1)
    stageA(1, t + 2, 0);
    BAR;
    SP(1); MFMA_Q2(0, 1, A0f, B1f); SP(0);
    loadA(1, b1, A1f);
    BAR;
    // P7: Q(1,1|t+1); no reads
    stageB(0, t + 3, 1);
    BAR;
    SP(1); MFMA_Q2(1, 1, A1f, B1f); SP(0);
    BAR;
    // P8: Q(1,0|t+1); VMCNT completes tile t+2 -> post-read A0,B0(t+2)
    if constexpr (NBH == 2) stageB(1, t + 3, 1);
    VMCNT(VMC);
    BAR;
    SP(1); MFMA_Q2(1, 0, A1f, B0f); SP(0);
    loadA(0, b0, A0f); loadB(0, b0, B0f);
    BAR;
  }

  // ---- tail K-tile (odd nk): buf0 holds tile nk-1; A0f/B0f pre-read at last P8 ----
  if (nk & 1) {
    SP(1); MFMA_Q2(0, 0, A0f, B0f); SP(0);
    loadB(1, b0, B1f);
    SP(1); MFMA_Q2(0, 1, A0f, B1f); SP(0);
    loadA(1, b0, A1f);
    SP(1); MFMA_Q2(1, 1, A1f, B1f); MFMA_Q2(1, 0, A1f, B0f); SP(0);
  }

  // ---- epilogue ----
  if constexpr (MODE == 2) {
    // out: plain f32 stores. C/D map col=lane&15, row=(lane>>4)*4+j.
    float* C = (float*)Cv;
#pragma unroll
    for (int im = 0; im < FM; ++im) {
#pragma unroll
      for (int in_ = 0; in_ < FNW; ++in_) {
        const int col = n0 + wcn * (BN / 4) + in_ * 16 + l15;
#pragma unroll
        for (int j = 0; j < 4; ++j) {
          const int row = m0 + wr * (BM / 2) + im * 16 + lhi * 4 + j;
          C[(size_t)row * N + col] = acc[im][in_][j];
        }
      }
    }
  } else {
    // MODE 3 (h, BM=256/BN=128): spill relu(h+b1) -> LDS hs[256][132] bf16,
    // then logits-GEMM vs W2b (bf16 [16][512], rows 8..15 zero) via MFMA.
    u16* hs = (u16*)lds;
    __syncthreads();  // drains vmcnt/lgkm (in-flight clamped prefetches) + barrier
#pragma unroll
    for (int im = 0; im < FM; ++im) {
#pragma unroll
      for (int in_ = 0; in_ < FNW; ++in_) {
        const int col = wcn * (BN / 4) + in_ * 16 + l15;  // block-local col
#pragma unroll
        for (int j = 0; j < 4; ++j) {
          const int row = wr * (BM / 2) + im * 16 + lhi * 4 + j;
          float v = fmaxf(acc[im][in_][j] + aux[n0 + col], 0.f);
          hs[row * 132 + col] = f2bf(v);
        }
      }
    }
    __syncthreads();
    // logits[256 x 8] = hs[256 x 128] @ W2b[.., n0..n0+127]^T. Wave w: rows w*32..+32.
    const u16* w2b = (const u16*)A2;
    f32x4 acc2[2] = {};
#pragma unroll
    for (int ks = 0; ks < 4; ++ks) {
      bf16x8 bfrag = *(const bf16x8*)(w2b + (size_t)l15 * 512 + n0 + ks * 32 + lhi * 8);
#pragma unroll
      for (int im2 = 0; im2 < 2; ++im2) {
        const int mrow = w * 32 + im2 * 16 + l15;
        bf16x8 afrag = *(const bf16x8*)(hs + mrow * 132 + ks * 32 + lhi * 8);
        acc2[im2] = __builtin_amdgcn_mfma_f32_16x16x32_bf16(afrag, bfrag, acc2[im2],
                                                            0, 0, 0);
      }
    }
    if (l15 < 8) {
      float* part = (float*)Cv;
      const size_t base = (size_t)(n0 >> 7) * M_TOK;
#pragma unroll
      for (int im2 = 0; im2 < 2; ++im2)
#pragma unroll
        for (int j = 0; j < 4; ++j) {
          const int row = m0 + w * 32 + im2 * 16 + lhi * 4 + j;
          part[(base + row) * 8 + l15] = acc2[im2][j];
        }
    }
  }
}

extern "C" void kernel_launch(void* const* d_in, const int* in_sizes, int n_in,
                              void* d_out, int out_size, void* d_ws, size_t ws_size,
                              hipStream_t stream) {
  const float* x     = (const float*)d_in[0];  // [16384][1024]
  const float* Wb    = (const float*)d_in[1];  // [1024][1024]
  const float* rW1   = (const float*)d_in[2];  // [512][1024]
  const float* rb1   = (const float*)d_in[3];  // [512]
  const float* rW2   = (const float*)d_in[4];  // [8][512]
  const float* rb2   = (const float*)d_in[5];  // [8]
  const float* temp  = (const float*)d_in[6];  // [1]
  const float* loraA = (const float*)d_in[7];  // [64][1024]
  const float* loraB = (const float*)d_in[8];  // [8][1024][8]
  float* out = (float*)d_out;

  uint8_t* p = (uint8_t*)d_ws;
  u16* xb    = (u16*)p;   p += (size_t)M_TOK * 1024 * 2;
  u16* wb    = (u16*)p;   p += (size_t)M_TOK * 64 * 2;
  u16* Btb   = (u16*)p;   p += (size_t)1024 * 1088 * 2;
  u16* W1b   = (u16*)p;   p += (size_t)512 * 1024 * 2;
  u16* W2b   = (u16*)p;   p += (size_t)16 * 512 * 2;
  u16* A2b   = (u16*)p;   p += (size_t)64 * 1024 * 2;
  float* part = (float*)p;  // [4][16384][8] f32 = 2 MB

  // ---- fused prep (incl. W2 -> bf16 padded [16][512]) ----
  prep_k<<<18248, 256, 0, stream>>>(x, Wb, rW1, rW2, loraA, loraB,
                                    xb, Btb, W1b, W2b, A2b);

  // ---- h-GEMM: MFMA router partials, no h materialization ----
  gemm8p<256, 128, 3><<<256, 512, 0, stream>>>(xb, W1b, (const u16*)W2b, part,
                                               rb1, 512, 1024, 1024, 1024);

  // ---- w = (x @ A^T) * softmax-gates (fused) -> bf16 [16384][64] ----
  gemm_w<<<dim3(1, M_TOK / 64), 256, 0, stream>>>(xb, A2b, part, rb2, temp, wb);

  // ---- out = [x | w] @ [Wb^T ; B2] -> f32, K=1088 ----
  gemm8p<256, 256, 2><<<256, 512, 0, stream>>>(xb, Btb, wb, out, nullptr,
                                               1024, 1088, 1024, 1088);
}